// Round 1
// baseline (1055.595 us; speedup 1.0000x reference)
//
#include <hip/hip_runtime.h>
#include <hip/hip_bf16.h>
#include <math.h>

#define EPB 64
#define ALPHA 0.17677669529663687f
#define INV_SQRT3 0.57735026918962576f

__device__ __forceinline__ float silu_f(float x) { return x / (1.0f + __expf(-x)); }
__device__ __forceinline__ float bflo(unsigned int u) { return __uint_as_float(u << 16); }
__device__ __forceinline__ float bfhi(unsigned int u) { return __uint_as_float(u & 0xffff0000u); }
__device__ __forceinline__ void ld4f(float* d, const float* s) {
  float4 t = *(const float4*)s; d[0] = t.x; d[1] = t.y; d[2] = t.z; d[3] = t.w;
}

// ---------------------------------------------------------------------------
// Edge kernel: fused radial-MLP + tensor-product message + scatter-add.
// Block = 256 threads, 64 edges. d_out doubles as the (N x 64) agg buffer.
// LDS budget: 62720 B (< 64 KB static limit) -> 2 blocks/CU -> 2 waves/SIMD.
// ---------------------------------------------------------------------------
__global__ __launch_bounds__(256, 2) void tfn_edge_kernel(
    const float* __restrict__ nf,     // N x 64
    const float* __restrict__ esh,    // E x 4
    const float* __restrict__ emb,    // E x 16
    const float* __restrict__ w1g,    // 16 x 64
    const float* __restrict__ b1g,    // 64
    const float* __restrict__ w2g,    // 64 x 1024
    const float* __restrict__ b2g,    // 1024
    const int*   __restrict__ eidx,   // 2 x E
    float* __restrict__ agg,          // N x 64 (pre-zeroed)
    int E)
{
  __shared__ __align__(16) __hip_bfloat16 hsm[EPB * 72];   // h, stride 72 (pad)
  __shared__ __align__(16) float wsm[64 * 68];             // w2 tile, stride 68 (pad)
  __shared__ __align__(16) __hip_bfloat16 f_xs[EPB * 16];  // xs
  __shared__ __align__(16) __hip_bfloat16 f_b [EPB * 16];  // sum_i xv*shv
  __shared__ __align__(16) __hip_bfloat16 f_xv[EPB * 48];  // xv*shs
  __shared__ __align__(16) float tbuf[EPB * 96];           // t0[16] t1[16] t2[16] t3[48]
  __shared__ float shs_l[EPB];
  __shared__ float shv_l[EPB * 3];
  __shared__ int   dst_l[EPB];

  const int tid = threadIdx.x;
  const int ebase = blockIdx.x * EPB;

  float* embs = (float*)wsm;         // [64][16]  (overlay, dead after layer 1)
  float* w1s  = (float*)wsm + 1024;  // [16][64]

  // ---------------- phase 0: stage inputs, per-edge factors ----------------
  {
    const int e = tid >> 2, p = tid & 3;
    int eg = ebase + e; if (eg >= E) eg = E - 1;

    float4 em = *(const float4*)&emb[(size_t)eg * 16 + p * 4];
    *(float4*)&embs[e * 16 + p * 4] = em;

    if (p == 0) {
      float4 sh = *(const float4*)&esh[(size_t)eg * 4];
      shs_l[e] = sh.x;
      shv_l[e * 3 + 0] = sh.y; shv_l[e * 3 + 1] = sh.z; shv_l[e * 3 + 2] = sh.w;
      dst_l[e] = eidx[E + eg];
    }

    const int src = eidx[eg];
    const float* row = nf + (size_t)src * 64;
    const float shs = esh[(size_t)eg * 4 + 0];
    const float sv0 = esh[(size_t)eg * 4 + 1];
    const float sv1 = esh[(size_t)eg * 4 + 2];
    const float sv2 = esh[(size_t)eg * 4 + 3];
    #pragma unroll
    for (int uu = 0; uu < 4; ++uu) {
      const int u = p * 4 + uu;
      const float xs = row[u];
      const float x0 = row[16 + u * 3 + 0];
      const float x1 = row[16 + u * 3 + 1];
      const float x2 = row[16 + u * 3 + 2];
      f_xs[e * 16 + u] = __float2bfloat16(xs);
      f_b [e * 16 + u] = __float2bfloat16(x0 * sv0 + x1 * sv1 + x2 * sv2);
      f_xv[e * 48 + u * 3 + 0] = __float2bfloat16(x0 * shs);
      f_xv[e * 48 + u * 3 + 1] = __float2bfloat16(x1 * shs);
      f_xv[e * 48 + u * 3 + 2] = __float2bfloat16(x2 * shs);
    }
  }
  {
    const int r = tid >> 4, q = (tid & 15) * 4;
    *(float4*)&w1s[r * 64 + q] = *(const float4*)&w1g[r * 64 + q];
  }
  for (int i = tid; i < EPB * 96; i += 256) tbuf[i] = 0.0f;
  __syncthreads();

  // ---------------- layer 1: h = silu(emb @ w1 + b1), bf16 into LDS -------
  {
    const int e = tid >> 2, p = tid & 3;
    #pragma unroll
    for (int kk = 0; kk < 16; ++kk) {
      const int c = p * 16 + kk;
      float acc = b1g[c];
      #pragma unroll
      for (int j = 0; j < 16; ++j) acc = fmaf(embs[e * 16 + j], w1s[j * 64 + c], acc);
      hsm[e * 72 + c] = __float2bfloat16(silu_f(acc));
    }
  }

  // ---------------- main loop: 4 sections x 4 col-tiles of 64 --------------
  const int eg2 = tid >> 3;          // 0..31
  const int cg  = tid & 7;           // 0..7
  const int e0  = eg2 * 2, e1 = e0 + 1;
  const int cb  = cg * 8;            // col base within tile
  const int vb  = (cg & 1) * 8;      // v base
  // shs_l was synced above
  const float shs0 = shs_l[e0], shs1 = shs_l[e1];

  #pragma unroll 1
  for (int sec = 0; sec < 4; ++sec) {
    float tr [2][8];
    float tr3[2][8][3];
    #pragma unroll
    for (int a = 0; a < 2; ++a)
      #pragma unroll
      for (int c = 0; c < 8; ++c) {
        tr[a][c] = 0.0f;
        tr3[a][c][0] = 0.0f; tr3[a][c][1] = 0.0f; tr3[a][c][2] = 0.0f;
      }

    #pragma unroll 1
    for (int t4 = 0; t4 < 4; ++t4) {
      const int c0 = sec * 256 + t4 * 64;
      __syncthreads();   // previous tile's reads (or layer-1 overlay reads) done
      {
        const int r = tid >> 4, q = (tid & 15) * 4;
        #pragma unroll
        for (int rr = 0; rr < 4; ++rr) {
          const int row = r + rr * 16;
          *(float4*)&wsm[row * 68 + q] = *(const float4*)&w2g[(size_t)row * 1024 + c0 + q];
        }
      }
      __syncthreads();

      float acc[2][8];
      #pragma unroll
      for (int a = 0; a < 2; ++a)
        #pragma unroll
        for (int c = 0; c < 8; ++c) acc[a][c] = 0.0f;

      #pragma unroll 2
      for (int ks = 0; ks < 64; ks += 8) {
        const uint4 hu0 = *(const uint4*)&hsm[e0 * 72 + ks];
        const uint4 hu1 = *(const uint4*)&hsm[e1 * 72 + ks];
        float ha0[8] = { bflo(hu0.x), bfhi(hu0.x), bflo(hu0.y), bfhi(hu0.y),
                         bflo(hu0.z), bfhi(hu0.z), bflo(hu0.w), bfhi(hu0.w) };
        float ha1[8] = { bflo(hu1.x), bfhi(hu1.x), bflo(hu1.y), bfhi(hu1.y),
                         bflo(hu1.z), bfhi(hu1.z), bflo(hu1.w), bfhi(hu1.w) };
        #pragma unroll
        for (int j = 0; j < 8; ++j) {
          float wv[8];
          ld4f(wv,     &wsm[(ks + j) * 68 + cb]);
          ld4f(wv + 4, &wsm[(ks + j) * 68 + cb + 4]);
          #pragma unroll
          for (int c = 0; c < 8; ++c) {
            acc[0][c] = fmaf(ha0[j], wv[c], acc[0][c]);
            acc[1][c] = fmaf(ha1[j], wv[c], acc[1][c]);
          }
        }
      }

      // epilogue: tpw = acc + b2 ; accumulate u-contraction into registers
      const int u = t4 * 4 + (cg >> 1);
      float b2v[8];
      ld4f(b2v,     &b2g[c0 + cb]);
      ld4f(b2v + 4, &b2g[c0 + cb + 4]);

      if (sec == 0) {            // W00, factor xs*shs -> t0
        const float f0 = __bfloat162float(f_xs[e0 * 16 + u]) * shs0;
        const float f1 = __bfloat162float(f_xs[e1 * 16 + u]) * shs1;
        #pragma unroll
        for (int c = 0; c < 8; ++c) {
          tr[0][c] = fmaf(f0, acc[0][c] + b2v[c], tr[0][c]);
          tr[1][c] = fmaf(f1, acc[1][c] + b2v[c], tr[1][c]);
        }
      } else if (sec == 1) {     // W01, factor xs -> t2
        const float f0 = __bfloat162float(f_xs[e0 * 16 + u]);
        const float f1 = __bfloat162float(f_xs[e1 * 16 + u]);
        #pragma unroll
        for (int c = 0; c < 8; ++c) {
          tr[0][c] = fmaf(f0, acc[0][c] + b2v[c], tr[0][c]);
          tr[1][c] = fmaf(f1, acc[1][c] + b2v[c], tr[1][c]);
        }
      } else if (sec == 2) {     // W10, factor xv*shs -> t3[i]
        float g0[3], g1[3];
        #pragma unroll
        for (int i = 0; i < 3; ++i) {
          g0[i] = __bfloat162float(f_xv[e0 * 48 + u * 3 + i]);
          g1[i] = __bfloat162float(f_xv[e1 * 48 + u * 3 + i]);
        }
        #pragma unroll
        for (int c = 0; c < 8; ++c) {
          const float tp0 = acc[0][c] + b2v[c];
          const float tp1 = acc[1][c] + b2v[c];
          #pragma unroll
          for (int i = 0; i < 3; ++i) {
            tr3[0][c][i] = fmaf(g0[i], tp0, tr3[0][c][i]);
            tr3[1][c][i] = fmaf(g1[i], tp1, tr3[1][c][i]);
          }
        }
      } else {                   // W11, factor sum_i(xv*shv) -> t1
        const float f0 = __bfloat162float(f_b[e0 * 16 + u]);
        const float f1 = __bfloat162float(f_b[e1 * 16 + u]);
        #pragma unroll
        for (int c = 0; c < 8; ++c) {
          tr[0][c] = fmaf(f0, acc[0][c] + b2v[c], tr[0][c]);
          tr[1][c] = fmaf(f1, acc[1][c] + b2v[c], tr[1][c]);
        }
      }
    } // t4

    // flush register partials into LDS t-buffer
    if (sec == 2) {
      #pragma unroll
      for (int a = 0; a < 2; ++a) {
        const int e = e0 + a;
        #pragma unroll
        for (int c = 0; c < 8; ++c) {
          const int v = vb + c;
          atomicAdd(&tbuf[e * 96 + 48 + v * 3 + 0], tr3[a][c][0]);
          atomicAdd(&tbuf[e * 96 + 48 + v * 3 + 1], tr3[a][c][1]);
          atomicAdd(&tbuf[e * 96 + 48 + v * 3 + 2], tr3[a][c][2]);
        }
      }
    } else {
      const int off = (sec == 0) ? 0 : ((sec == 1) ? 32 : 16);
      #pragma unroll
      for (int a = 0; a < 2; ++a)
        #pragma unroll
        for (int c = 0; c < 8; ++c)
          atomicAdd(&tbuf[(e0 + a) * 96 + off + vb + c], tr[a][c]);
    }
  } // sec

  __syncthreads();

  // ---------------- combine + scatter-add to agg ---------------------------
  {
    const int e = tid >> 2, p = tid & 3;
    if (ebase + e < E) {
      const int dst = dst_l[e];
      const float sv0 = shv_l[e * 3 + 0], sv1 = shv_l[e * 3 + 1], sv2 = shv_l[e * 3 + 2];
      const float* tb = &tbuf[e * 96];
      if (p == 0) {
        #pragma unroll
        for (int v = 0; v < 16; ++v) {
          const float msg = ALPHA * (tb[v] + INV_SQRT3 * tb[16 + v]);
          atomicAdd(&agg[(size_t)dst * 64 + v], msg);
        }
      } else {
        #pragma unroll
        for (int oo = 0; oo < 16; ++oo) {
          const int q = (p - 1) * 16 + oo;    // 0..47
          const int v = q / 3, i = q - v * 3;
          const float sh = (i == 0) ? sv0 : ((i == 1) ? sv1 : sv2);
          const float msg = ALPHA * (tb[32 + v] * sh + tb[48 + q]);
          atomicAdd(&agg[(size_t)dst * 64 + 16 + q], msg);
        }
      }
    }
  }
}

// ---------------------------------------------------------------------------
// Node kernel: linear mix + gated activations + residual, in place on d_out.
// ---------------------------------------------------------------------------
__global__ __launch_bounds__(256) void tfn_node_kernel(
    const float* __restrict__ nf,
    const float* __restrict__ lw0,
    const float* __restrict__ lw1,
    float* __restrict__ out, int N)
{
  __shared__ float w0s[256], w1s[256];
  const int tid = threadIdx.x;
  w0s[tid] = lw0[tid];
  w1s[tid] = lw1[tid];
  __syncthreads();

  const int n = blockIdx.x * 256 + tid;
  if (n >= N) return;

  float* rowp = out + (size_t)n * 64;
  float as[16], av[16][3];
  #pragma unroll
  for (int u = 0; u < 16; ++u) as[u] = rowp[u];
  #pragma unroll
  for (int u = 0; u < 16; ++u) {
    av[u][0] = rowp[16 + u * 3 + 0];
    av[u][1] = rowp[16 + u * 3 + 1];
    av[u][2] = rowp[16 + u * 3 + 2];
  }
  const float* nfr = nf + (size_t)n * 64;
  float res[64];

  #pragma unroll
  for (int v = 0; v < 16; ++v) {
    float acc = 0.0f;
    #pragma unroll
    for (int u = 0; u < 16; ++u) acc = fmaf(as[u], w0s[u * 16 + v], acc);
    const float ts = 0.25f * acc;
    const float ns = fabsf(ts);
    const float g = (ns / (1.0f + __expf(-ns))) / (ns + 1e-8f);
    res[v] = nfr[v] + ts * g;
  }
  #pragma unroll
  for (int v = 0; v < 16; ++v) {
    float a0 = 0.0f, a1 = 0.0f, a2 = 0.0f;
    #pragma unroll
    for (int u = 0; u < 16; ++u) {
      const float w = w1s[u * 16 + v];
      a0 = fmaf(av[u][0], w, a0);
      a1 = fmaf(av[u][1], w, a1);
      a2 = fmaf(av[u][2], w, a2);
    }
    a0 *= 0.25f; a1 *= 0.25f; a2 *= 0.25f;
    const float nv = sqrtf(a0 * a0 + a1 * a1 + a2 * a2);
    const float g = (nv / (1.0f + __expf(-nv))) / (nv + 1e-8f);
    res[16 + v * 3 + 0] = nfr[16 + v * 3 + 0] + a0 * g;
    res[16 + v * 3 + 1] = nfr[16 + v * 3 + 1] + a1 * g;
    res[16 + v * 3 + 2] = nfr[16 + v * 3 + 2] + a2 * g;
  }
  #pragma unroll
  for (int o = 0; o < 64; o += 4) {
    *(float4*)&rowp[o] = make_float4(res[o], res[o + 1], res[o + 2], res[o + 3]);
  }
}

extern "C" void kernel_launch(void* const* d_in, const int* in_sizes, int n_in,
                              void* d_out, int out_size, void* d_ws, size_t ws_size,
                              hipStream_t stream) {
  const float* nf  = (const float*)d_in[0];
  const float* esh = (const float*)d_in[1];
  const float* emb = (const float*)d_in[2];
  const float* w1  = (const float*)d_in[3];
  const float* b1  = (const float*)d_in[4];
  const float* w2  = (const float*)d_in[5];
  const float* b2  = (const float*)d_in[6];
  const float* lw0 = (const float*)d_in[7];
  const float* lw1 = (const float*)d_in[8];
  const int*   eix = (const int*)d_in[9];

  const int N = in_sizes[0] / 64;
  const int E = in_sizes[9] / 2;
  float* out = (float*)d_out;

  hipMemsetAsync(out, 0, (size_t)out_size * sizeof(float), stream);

  const int eblocks = (E + EPB - 1) / EPB;
  tfn_edge_kernel<<<dim3(eblocks), dim3(256), 0, stream>>>(
      nf, esh, emb, w1, b1, w2, b2, eix, out, E);

  const int nblocks = (N + 255) / 256;
  tfn_node_kernel<<<dim3(nblocks), dim3(256), 0, stream>>>(nf, lw0, lw1, out, N);
}

// Round 2
// 673.658 us; speedup vs baseline: 1.5670x; 1.5670x over previous
//
#include <hip/hip_runtime.h>
#include <hip/hip_bf16.h>
#include <math.h>

#define EPB 64
#define ALPHA 0.17677669529663687f
#define INV_SQRT3 0.57735026918962576f

typedef __attribute__((ext_vector_type(8))) short short8;
typedef __attribute__((ext_vector_type(4))) float f32x4;

__device__ __forceinline__ float silu_f(float x) { return x / (1.0f + __expf(-x)); }

__device__ __forceinline__ unsigned short bf16_rne(float x) {
  unsigned int u = __float_as_uint(x);
  unsigned int r = u + 0x7fffu + ((u >> 16) & 1u);
  return (unsigned short)(r >> 16);
}

// ---------------------------------------------------------------------------
// Prep: w2 (64 x 1024 fp32, row-major) -> w2t (1024 x 64 bf16) in d_ws.
// 16 blocks x 256 threads; LDS transpose so both global accesses coalesce.
// ---------------------------------------------------------------------------
__global__ __launch_bounds__(256) void w2t_kernel(const float* __restrict__ w2,
                                                  unsigned short* __restrict__ w2t) {
  __shared__ unsigned short tile[16][260];
  const int t = threadIdx.x;
  const int k0 = (blockIdx.x & 3) * 16;
  const int c0 = (blockIdx.x >> 2) * 256;
  #pragma unroll
  for (int j = 0; j < 16; ++j)
    tile[j][t] = bf16_rne(w2[(size_t)(k0 + j) * 1024 + c0 + t]);
  __syncthreads();
  union { unsigned short s[16]; uint4 q[2]; } pk;
  #pragma unroll
  for (int j = 0; j < 16; ++j) pk.s[j] = tile[j][t];
  uint4* dst = (uint4*)&w2t[(size_t)(c0 + t) * 64 + k0];
  dst[0] = pk.q[0];
  dst[1] = pk.q[1];
}

// ---------------------------------------------------------------------------
// Edge kernel: fused radial-MLP + MFMA tensor-product + scatter-add.
// Block = 256 threads = 4 waves; wave w handles section w (W00,W01,W10,W11).
// 64 edges/block. d_out doubles as the (N x 64) agg buffer.
// LDS: 63744 B -> 2 blocks/CU.
// ---------------------------------------------------------------------------
__global__ __launch_bounds__(256, 2) void tfn_edge_kernel(
    const float* __restrict__ nf,     // N x 64
    const float* __restrict__ esh,    // E x 4
    const float* __restrict__ emb,    // E x 16
    const float* __restrict__ w1g,    // 16 x 64
    const float* __restrict__ b1g,    // 64
    const unsigned short* __restrict__ w2t, // 1024 x 64 bf16 (transposed)
    const float* __restrict__ b2g,    // 1024
    const int*   __restrict__ eidx,   // 2 x E
    float* __restrict__ agg,          // N x 64 (pre-zeroed)
    int E)
{
  __shared__ __align__(16) unsigned short hsm[EPB * 72];  // h bf16, stride 72
  __shared__ __align__(16) float fsT[16 * 72];            // xs,        [u][e]
  __shared__ __align__(16) float fbT[16 * 72];            // xv.shv,    [u][e]
  __shared__ __align__(16) float fxvT[3 * 16 * 72];       // raw xv_i,  [i][u][e]
  __shared__ __align__(16) float b2s[1024];
  __shared__ __align__(16) float t01[2 * 1088];           // t0 | t1, [e*17+v]
  __shared__ __align__(16) float t2s[1088];
  __shared__ __align__(16) float t3s[3 * 1088];           // [i][e*17+v]
  __shared__ float shs_l[EPB];
  __shared__ float shv_l[EPB * 3];
  __shared__ int   dst_l[EPB];

  const int tid = threadIdx.x;
  const int ebase = blockIdx.x * EPB;

  float* embs = t01;          // overlay: [64][16], dead after layer 1
  float* w1s  = t01 + 1024;   // overlay: [16][64]

  // ---------------- phase 0: stage inputs + factor tables ------------------
  {
    const int e = tid >> 2, p = tid & 3;
    int eg = ebase + e; if (eg >= E) eg = E - 1;

    float4 em = *(const float4*)&emb[(size_t)eg * 16 + p * 4];
    *(float4*)&embs[e * 16 + p * 4] = em;

    if (p == 0) {
      float4 sh = *(const float4*)&esh[(size_t)eg * 4];
      shs_l[e] = sh.x;
      shv_l[e * 3 + 0] = sh.y; shv_l[e * 3 + 1] = sh.z; shv_l[e * 3 + 2] = sh.w;
      dst_l[e] = eidx[E + eg];
    }

    const int src = eidx[eg];
    const float* row = nf + (size_t)src * 64;
    const float sv0 = esh[(size_t)eg * 4 + 1];
    const float sv1 = esh[(size_t)eg * 4 + 2];
    const float sv2 = esh[(size_t)eg * 4 + 3];
    #pragma unroll
    for (int uu = 0; uu < 4; ++uu) {
      const int u = p * 4 + uu;
      const float xs = row[u];
      const float x0 = row[16 + u * 3 + 0];
      const float x1 = row[16 + u * 3 + 1];
      const float x2 = row[16 + u * 3 + 2];
      fsT[u * 72 + e] = xs;
      fbT[u * 72 + e] = x0 * sv0 + x1 * sv1 + x2 * sv2;
      fxvT[(0 * 16 + u) * 72 + e] = x0;
      fxvT[(1 * 16 + u) * 72 + e] = x1;
      fxvT[(2 * 16 + u) * 72 + e] = x2;
    }
  }
  {
    const int r = tid >> 4, q = (tid & 15) * 4;
    *(float4*)&w1s[r * 64 + q] = *(const float4*)&w1g[r * 64 + q];
  }
  *(float4*)&b2s[tid * 4] = *(const float4*)&b2g[tid * 4];
  __syncthreads();

  // ---------------- layer 1: h = silu(emb @ w1 + b1) -> bf16 LDS -----------
  {
    const int e = tid >> 2, p = tid & 3;
    #pragma unroll
    for (int kk = 0; kk < 16; ++kk) {
      const int c = p * 16 + kk;
      float acc = b1g[c];
      #pragma unroll
      for (int j = 0; j < 16; ++j) acc = fmaf(embs[e * 16 + j], w1s[j * 64 + c], acc);
      hsm[e * 72 + c] = bf16_rne(silu_f(acc));
    }
  }
  __syncthreads();

  // ---------------- main loop: wave = section, MFMA over 16 u-tiles --------
  const int lane = tid & 63;
  const int sec  = tid >> 6;           // wave-uniform
  const int q = lane >> 4, m = lane & 15;

  // A fragments: h rows for all 4 M-tiles, both K-steps. Stays in regs.
  union AF { uint4 u4; short8 s8; };
  AF afr[4][2];
  #pragma unroll
  for (int mt = 0; mt < 4; ++mt)
    #pragma unroll
    for (int ks = 0; ks < 2; ++ks)
      afr[mt][ks].u4 = *(const uint4*)&hsm[(mt * 16 + m) * 72 + ks * 32 + q * 8];

  const float* ftab = (sec == 3) ? fbT : fsT;   // sec 0,1 -> fs; sec 3 -> fb
  const uint4* w2tq = (const uint4*)w2t;

  float acc [4][4];
  float acc3[4][4][3];
  #pragma unroll
  for (int mt = 0; mt < 4; ++mt)
    #pragma unroll
    for (int r = 0; r < 4; ++r) {
      acc[mt][r] = 0.0f;
      acc3[mt][r][0] = 0.0f; acc3[mt][r][1] = 0.0f; acc3[mt][r][2] = 0.0f;
    }

  #pragma unroll 2
  for (int u = 0; u < 16; ++u) {
    const int col = sec * 256 + u * 16 + m;
    union AF b0, b1;
    const uint4* bp = w2tq + (size_t)col * 8 + q;
    b0.u4 = bp[0];
    b1.u4 = bp[4];
    const float b2v = b2s[col];

    #pragma unroll
    for (int mt = 0; mt < 4; ++mt) {
      f32x4 c = {0.0f, 0.0f, 0.0f, 0.0f};
      c = __builtin_amdgcn_mfma_f32_16x16x32_bf16(afr[mt][0].s8, b0.s8, c, 0, 0, 0);
      c = __builtin_amdgcn_mfma_f32_16x16x32_bf16(afr[mt][1].s8, b1.s8, c, 0, 0, 0);

      if (sec == 2) {
        const float4 f0 = *(const float4*)&fxvT[(0 * 16 + u) * 72 + mt * 16 + q * 4];
        const float4 f1 = *(const float4*)&fxvT[(1 * 16 + u) * 72 + mt * 16 + q * 4];
        const float4 f2 = *(const float4*)&fxvT[(2 * 16 + u) * 72 + mt * 16 + q * 4];
        const float ff0[4] = {f0.x, f0.y, f0.z, f0.w};
        const float ff1[4] = {f1.x, f1.y, f1.z, f1.w};
        const float ff2[4] = {f2.x, f2.y, f2.z, f2.w};
        #pragma unroll
        for (int r = 0; r < 4; ++r) {
          const float tp = c[r] + b2v;
          acc3[mt][r][0] = fmaf(ff0[r], tp, acc3[mt][r][0]);
          acc3[mt][r][1] = fmaf(ff1[r], tp, acc3[mt][r][1]);
          acc3[mt][r][2] = fmaf(ff2[r], tp, acc3[mt][r][2]);
        }
      } else {
        const float4 f = *(const float4*)&ftab[u * 72 + mt * 16 + q * 4];
        const float ff[4] = {f.x, f.y, f.z, f.w};
        #pragma unroll
        for (int r = 0; r < 4; ++r)
          acc[mt][r] = fmaf(ff[r], c[r] + b2v, acc[mt][r]);
      }
    }
  }

  // ---------------- flush wave partials to LDS ------------------------------
  #pragma unroll
  for (int mt = 0; mt < 4; ++mt)
    #pragma unroll
    for (int r = 0; r < 4; ++r) {
      const int e = mt * 16 + q * 4 + r;
      if (sec == 0)      t01[e * 17 + m]        = acc[mt][r] * shs_l[e];
      else if (sec == 1) t2s[e * 17 + m]        = acc[mt][r];
      else if (sec == 3) t01[1088 + e * 17 + m] = acc[mt][r];
      else {
        const float s = shs_l[e];
        t3s[0 * 1088 + e * 17 + m] = acc3[mt][r][0] * s;
        t3s[1 * 1088 + e * 17 + m] = acc3[mt][r][1] * s;
        t3s[2 * 1088 + e * 17 + m] = acc3[mt][r][2] * s;
      }
    }
  __syncthreads();

  // ---------------- combine + scatter-add to agg ---------------------------
  {
    const int e = tid >> 2, p = tid & 3;
    if (ebase + e < E) {
      const int dst = dst_l[e];
      if (p == 0) {
        #pragma unroll
        for (int v = 0; v < 16; ++v) {
          const float msg = ALPHA * (t01[e * 17 + v] + INV_SQRT3 * t01[1088 + e * 17 + v]);
          atomicAdd(&agg[(size_t)dst * 64 + v], msg);
        }
      } else {
        #pragma unroll
        for (int oo = 0; oo < 16; ++oo) {
          const int qq = (p - 1) * 16 + oo;    // 0..47
          const int v = qq / 3, i = qq - v * 3;
          const float sh = shv_l[e * 3 + i];
          const float msg = ALPHA * (t2s[e * 17 + v] * sh + t3s[i * 1088 + e * 17 + v]);
          atomicAdd(&agg[(size_t)dst * 64 + 16 + qq], msg);
        }
      }
    }
  }
}

// ---------------------------------------------------------------------------
// Node kernel: linear mix + gated activations + residual, in place on d_out.
// ---------------------------------------------------------------------------
__global__ __launch_bounds__(256) void tfn_node_kernel(
    const float* __restrict__ nf,
    const float* __restrict__ lw0,
    const float* __restrict__ lw1,
    float* __restrict__ out, int N)
{
  __shared__ float w0s[256], w1s[256];
  const int tid = threadIdx.x;
  w0s[tid] = lw0[tid];
  w1s[tid] = lw1[tid];
  __syncthreads();

  const int n = blockIdx.x * 256 + tid;
  if (n >= N) return;

  float* rowp = out + (size_t)n * 64;
  float as[16], av[16][3];
  #pragma unroll
  for (int u = 0; u < 16; ++u) as[u] = rowp[u];
  #pragma unroll
  for (int u = 0; u < 16; ++u) {
    av[u][0] = rowp[16 + u * 3 + 0];
    av[u][1] = rowp[16 + u * 3 + 1];
    av[u][2] = rowp[16 + u * 3 + 2];
  }
  const float* nfr = nf + (size_t)n * 64;
  float res[64];

  #pragma unroll
  for (int v = 0; v < 16; ++v) {
    float acc = 0.0f;
    #pragma unroll
    for (int u = 0; u < 16; ++u) acc = fmaf(as[u], w0s[u * 16 + v], acc);
    const float ts = 0.25f * acc;
    const float ns = fabsf(ts);
    const float g = (ns / (1.0f + __expf(-ns))) / (ns + 1e-8f);
    res[v] = nfr[v] + ts * g;
  }
  #pragma unroll
  for (int v = 0; v < 16; ++v) {
    float a0 = 0.0f, a1 = 0.0f, a2 = 0.0f;
    #pragma unroll
    for (int u = 0; u < 16; ++u) {
      const float w = w1s[u * 16 + v];
      a0 = fmaf(av[u][0], w, a0);
      a1 = fmaf(av[u][1], w, a1);
      a2 = fmaf(av[u][2], w, a2);
    }
    a0 *= 0.25f; a1 *= 0.25f; a2 *= 0.25f;
    const float nv = sqrtf(a0 * a0 + a1 * a1 + a2 * a2);
    const float g = (nv / (1.0f + __expf(-nv))) / (nv + 1e-8f);
    res[16 + v * 3 + 0] = nfr[16 + v * 3 + 0] + a0 * g;
    res[16 + v * 3 + 1] = nfr[16 + v * 3 + 1] + a1 * g;
    res[16 + v * 3 + 2] = nfr[16 + v * 3 + 2] + a2 * g;
  }
  #pragma unroll
  for (int o = 0; o < 64; o += 4) {
    *(float4*)&rowp[o] = make_float4(res[o], res[o + 1], res[o + 2], res[o + 3]);
  }
}

extern "C" void kernel_launch(void* const* d_in, const int* in_sizes, int n_in,
                              void* d_out, int out_size, void* d_ws, size_t ws_size,
                              hipStream_t stream) {
  const float* nf  = (const float*)d_in[0];
  const float* esh = (const float*)d_in[1];
  const float* emb = (const float*)d_in[2];
  const float* w1  = (const float*)d_in[3];
  const float* b1  = (const float*)d_in[4];
  const float* w2  = (const float*)d_in[5];
  const float* b2  = (const float*)d_in[6];
  const float* lw0 = (const float*)d_in[7];
  const float* lw1 = (const float*)d_in[8];
  const int*   eix = (const int*)d_in[9];

  const int N = in_sizes[0] / 64;
  const int E = in_sizes[9] / 2;
  float* out = (float*)d_out;
  unsigned short* w2t = (unsigned short*)d_ws;   // 1024 x 64 bf16 = 128 KB

  w2t_kernel<<<dim3(16), dim3(256), 0, stream>>>(w2, w2t);

  hipMemsetAsync(out, 0, (size_t)out_size * sizeof(float), stream);

  const int eblocks = (E + EPB - 1) / EPB;
  tfn_edge_kernel<<<dim3(eblocks), dim3(256), 0, stream>>>(
      nf, esh, emb, w1, b1, w2t, b2, eix, out, E);

  const int nblocks = (N + 255) / 256;
  tfn_node_kernel<<<dim3(nblocks), dim3(256), 0, stream>>>(nf, lw0, lw1, out, N);
}

// Round 3
// 222.452 us; speedup vs baseline: 4.7453x; 3.0283x over previous
//
#include <hip/hip_runtime.h>
#include <hip/hip_bf16.h>
#include <math.h>

#define EPB 64
#define ALPHA 0.17677669529663687f
#define INV_SQRT3 0.57735026918962576f

typedef __attribute__((ext_vector_type(8))) short short8;
typedef __attribute__((ext_vector_type(4))) float f32x4;

__device__ __forceinline__ float silu_f(float x) { return x / (1.0f + __expf(-x)); }

__device__ __forceinline__ unsigned short bf16_rne(float x) {
  unsigned int u = __float_as_uint(x);
  unsigned int r = u + 0x7fffu + ((u >> 16) & 1u);
  return (unsigned short)(r >> 16);
}

// ---------------------------------------------------------------------------
// Prep: w2 (64 x 1024 fp32, row-major) -> w2t (1024 x 64 bf16) in d_ws.
// ---------------------------------------------------------------------------
__global__ __launch_bounds__(256) void w2t_kernel(const float* __restrict__ w2,
                                                  unsigned short* __restrict__ w2t) {
  __shared__ unsigned short tile[16][260];
  const int t = threadIdx.x;
  const int k0 = (blockIdx.x & 3) * 16;
  const int c0 = (blockIdx.x >> 2) * 256;
  #pragma unroll
  for (int j = 0; j < 16; ++j)
    tile[j][t] = bf16_rne(w2[(size_t)(k0 + j) * 1024 + c0 + t]);
  __syncthreads();
  union { unsigned short s[16]; uint4 q[2]; } pk;
  #pragma unroll
  for (int j = 0; j < 16; ++j) pk.s[j] = tile[j][t];
  uint4* dst = (uint4*)&w2t[(size_t)(c0 + t) * 64 + k0];
  dst[0] = pk.q[0];
  dst[1] = pk.q[1];
}

// ---------------------------------------------------------------------------
// CSR build: per-edge rank within its dst bucket (deg pre-zeroed).
// ---------------------------------------------------------------------------
__global__ __launch_bounds__(256) void count_kernel(const int* __restrict__ eidx,
                                                    int* __restrict__ deg,
                                                    int* __restrict__ rank, int E) {
  const int e = blockIdx.x * 256 + threadIdx.x;
  if (e < E) rank[e] = atomicAdd(&deg[eidx[E + e]], 1);
}

// Single-block exclusive prefix sum over N degrees -> offs[0..N].
__global__ __launch_bounds__(256) void scan_kernel(const int* __restrict__ deg,
                                                   int* __restrict__ offs, int N) {
  __shared__ int sums[256];
  const int t = threadIdx.x;
  const int ch = (N + 255) >> 8;
  const int lo = t * ch;
  const int hi = min(lo + ch, N);
  int s = 0;
  for (int i = lo; i < hi; ++i) s += deg[i];
  sums[t] = s;
  __syncthreads();
  #pragma unroll
  for (int d = 1; d < 256; d <<= 1) {
    int v = (t >= d) ? sums[t - d] : 0;
    __syncthreads();
    sums[t] += v;
    __syncthreads();
  }
  int run = sums[t] - s;   // exclusive base for this chunk
  for (int i = lo; i < hi; ++i) { offs[i] = run; run += deg[i]; }
  if (lo < N && hi == N) offs[N] = run;
}

// ---------------------------------------------------------------------------
// Edge kernel: fused radial-MLP + MFMA tensor-product. Messages written
// destination-sorted to msg[pos] (posmode) or atomically to agg (fallback).
// Block = 256 threads = 4 waves; wave w handles section w (W00,W01,W10,W11).
// ---------------------------------------------------------------------------
__global__ __launch_bounds__(256, 2) void tfn_edge_kernel(
    const float* __restrict__ nf,     // N x 64
    const float* __restrict__ esh,    // E x 4
    const float* __restrict__ emb,    // E x 16
    const float* __restrict__ w1g,    // 16 x 64
    const float* __restrict__ b1g,    // 64
    const unsigned short* __restrict__ w2t, // 1024 x 64 bf16 (transposed)
    const float* __restrict__ b2g,    // 1024
    const int*   __restrict__ eidx,   // 2 x E
    const int*   __restrict__ rank,   // E (posmode)
    const int*   __restrict__ offs,   // N+1 (posmode)
    float* __restrict__ msg,          // E x 64 dst-sorted (posmode)
    float* __restrict__ agg,          // N x 64 pre-zeroed (fallback)
    int E, int posmode)
{
  __shared__ __align__(16) unsigned short hsm[EPB * 72];  // h bf16, stride 72
  __shared__ __align__(16) float fsT[16 * 72];            // xs,        [u][e]
  __shared__ __align__(16) float fbT[16 * 72];            // xv.shv,    [u][e]
  __shared__ __align__(16) float fxvT[3 * 16 * 72];       // raw xv_i,  [i][u][e]
  __shared__ __align__(16) float b2s[1024];
  __shared__ __align__(16) float t01[2 * 1088];           // t0 | t1, [e*17+v]
  __shared__ __align__(16) float t2s[1088];
  __shared__ __align__(16) float t3s[3 * 1088];           // [i][e*17+v]
  __shared__ float shs_l[EPB];
  __shared__ float shv_l[EPB * 3];
  __shared__ int   pos_l[EPB];                            // pos (or dst in fallback)

  const int tid = threadIdx.x;
  const int ebase = blockIdx.x * EPB;

  float* embs = t01;          // overlay: [64][16], dead after layer 1
  float* w1s  = t01 + 1024;   // overlay: [16][64]

  // ---------------- phase 0: stage inputs + factor tables ------------------
  {
    const int e = tid >> 2, p = tid & 3;
    int eg = ebase + e; if (eg >= E) eg = E - 1;

    float4 em = *(const float4*)&emb[(size_t)eg * 16 + p * 4];
    *(float4*)&embs[e * 16 + p * 4] = em;

    if (p == 0) {
      float4 sh = *(const float4*)&esh[(size_t)eg * 4];
      shs_l[e] = sh.x;
      shv_l[e * 3 + 0] = sh.y; shv_l[e * 3 + 1] = sh.z; shv_l[e * 3 + 2] = sh.w;
      const int dst = eidx[E + eg];
      pos_l[e] = posmode ? (offs[dst] + rank[eg]) : dst;
    }

    const int src = eidx[eg];
    const float* row = nf + (size_t)src * 64;
    const float sv0 = esh[(size_t)eg * 4 + 1];
    const float sv1 = esh[(size_t)eg * 4 + 2];
    const float sv2 = esh[(size_t)eg * 4 + 3];
    #pragma unroll
    for (int uu = 0; uu < 4; ++uu) {
      const int u = p * 4 + uu;
      const float xs = row[u];
      const float x0 = row[16 + u * 3 + 0];
      const float x1 = row[16 + u * 3 + 1];
      const float x2 = row[16 + u * 3 + 2];
      fsT[u * 72 + e] = xs;
      fbT[u * 72 + e] = x0 * sv0 + x1 * sv1 + x2 * sv2;
      fxvT[(0 * 16 + u) * 72 + e] = x0;
      fxvT[(1 * 16 + u) * 72 + e] = x1;
      fxvT[(2 * 16 + u) * 72 + e] = x2;
    }
  }
  {
    const int r = tid >> 4, q = (tid & 15) * 4;
    *(float4*)&w1s[r * 64 + q] = *(const float4*)&w1g[r * 64 + q];
  }
  *(float4*)&b2s[tid * 4] = *(const float4*)&b2g[tid * 4];
  __syncthreads();

  // ---------------- layer 1: h = silu(emb @ w1 + b1) -> bf16 LDS -----------
  {
    const int e = tid >> 2, p = tid & 3;
    #pragma unroll
    for (int kk = 0; kk < 16; ++kk) {
      const int c = p * 16 + kk;
      float acc = b1g[c];
      #pragma unroll
      for (int j = 0; j < 16; ++j) acc = fmaf(embs[e * 16 + j], w1s[j * 64 + c], acc);
      hsm[e * 72 + c] = bf16_rne(silu_f(acc));
    }
  }
  __syncthreads();

  // ---------------- main loop: wave = section, MFMA over 16 u-tiles --------
  const int lane = tid & 63;
  const int sec  = tid >> 6;           // wave-uniform
  const int q = lane >> 4, m = lane & 15;

  union AF { uint4 u4; short8 s8; };
  AF afr[4][2];
  #pragma unroll
  for (int mt = 0; mt < 4; ++mt)
    #pragma unroll
    for (int ks = 0; ks < 2; ++ks)
      afr[mt][ks].u4 = *(const uint4*)&hsm[(mt * 16 + m) * 72 + ks * 32 + q * 8];

  const float* ftab = (sec == 3) ? fbT : fsT;
  const uint4* w2tq = (const uint4*)w2t;

  float acc [4][4];
  float acc3[4][4][3];
  #pragma unroll
  for (int mt = 0; mt < 4; ++mt)
    #pragma unroll
    for (int r = 0; r < 4; ++r) {
      acc[mt][r] = 0.0f;
      acc3[mt][r][0] = 0.0f; acc3[mt][r][1] = 0.0f; acc3[mt][r][2] = 0.0f;
    }

  #pragma unroll 2
  for (int u = 0; u < 16; ++u) {
    const int col = sec * 256 + u * 16 + m;
    union AF b0, b1;
    const uint4* bp = w2tq + (size_t)col * 8 + q;
    b0.u4 = bp[0];
    b1.u4 = bp[4];
    const float b2v = b2s[col];

    #pragma unroll
    for (int mt = 0; mt < 4; ++mt) {
      f32x4 c = {0.0f, 0.0f, 0.0f, 0.0f};
      c = __builtin_amdgcn_mfma_f32_16x16x32_bf16(afr[mt][0].s8, b0.s8, c, 0, 0, 0);
      c = __builtin_amdgcn_mfma_f32_16x16x32_bf16(afr[mt][1].s8, b1.s8, c, 0, 0, 0);

      if (sec == 2) {
        const float4 f0 = *(const float4*)&fxvT[(0 * 16 + u) * 72 + mt * 16 + q * 4];
        const float4 f1 = *(const float4*)&fxvT[(1 * 16 + u) * 72 + mt * 16 + q * 4];
        const float4 f2 = *(const float4*)&fxvT[(2 * 16 + u) * 72 + mt * 16 + q * 4];
        const float ff0[4] = {f0.x, f0.y, f0.z, f0.w};
        const float ff1[4] = {f1.x, f1.y, f1.z, f1.w};
        const float ff2[4] = {f2.x, f2.y, f2.z, f2.w};
        #pragma unroll
        for (int r = 0; r < 4; ++r) {
          const float tp = c[r] + b2v;
          acc3[mt][r][0] = fmaf(ff0[r], tp, acc3[mt][r][0]);
          acc3[mt][r][1] = fmaf(ff1[r], tp, acc3[mt][r][1]);
          acc3[mt][r][2] = fmaf(ff2[r], tp, acc3[mt][r][2]);
        }
      } else {
        const float4 f = *(const float4*)&ftab[u * 72 + mt * 16 + q * 4];
        const float ff[4] = {f.x, f.y, f.z, f.w};
        #pragma unroll
        for (int r = 0; r < 4; ++r)
          acc[mt][r] = fmaf(ff[r], c[r] + b2v, acc[mt][r]);
      }
    }
  }

  // ---------------- flush wave partials to LDS ------------------------------
  #pragma unroll
  for (int mt = 0; mt < 4; ++mt)
    #pragma unroll
    for (int r = 0; r < 4; ++r) {
      const int e = mt * 16 + q * 4 + r;
      if (sec == 0)      t01[e * 17 + m]        = acc[mt][r] * shs_l[e];
      else if (sec == 1) t2s[e * 17 + m]        = acc[mt][r];
      else if (sec == 3) t01[1088 + e * 17 + m] = acc[mt][r];
      else {
        const float s = shs_l[e];
        t3s[0 * 1088 + e * 17 + m] = acc3[mt][r][0] * s;
        t3s[1 * 1088 + e * 17 + m] = acc3[mt][r][1] * s;
        t3s[2 * 1088 + e * 17 + m] = acc3[mt][r][2] * s;
      }
    }
  __syncthreads();

  // ---------------- combine + emit messages --------------------------------
  {
    const int e = tid >> 2, p = tid & 3;
    if (ebase + e < E) {
      if (posmode) {
        float* mrow = msg + (size_t)pos_l[e] * 64;
        if (p == 0) {
          #pragma unroll
          for (int v = 0; v < 16; v += 4) {
            float4 o;
            o.x = ALPHA * (t01[e * 17 + v + 0] + INV_SQRT3 * t01[1088 + e * 17 + v + 0]);
            o.y = ALPHA * (t01[e * 17 + v + 1] + INV_SQRT3 * t01[1088 + e * 17 + v + 1]);
            o.z = ALPHA * (t01[e * 17 + v + 2] + INV_SQRT3 * t01[1088 + e * 17 + v + 2]);
            o.w = ALPHA * (t01[e * 17 + v + 3] + INV_SQRT3 * t01[1088 + e * 17 + v + 3]);
            *(float4*)&mrow[v] = o;
          }
        } else {
          #pragma unroll
          for (int oo = 0; oo < 16; oo += 4) {
            float vals[4];
            #pragma unroll
            for (int k = 0; k < 4; ++k) {
              const int qq = (p - 1) * 16 + oo + k;
              const int v = qq / 3, i = qq - v * 3;
              vals[k] = ALPHA * (t2s[e * 17 + v] * shv_l[e * 3 + i] + t3s[i * 1088 + e * 17 + v]);
            }
            *(float4*)&mrow[16 + (p - 1) * 16 + oo] = make_float4(vals[0], vals[1], vals[2], vals[3]);
          }
        }
      } else {
        const int dst = pos_l[e];
        if (p == 0) {
          #pragma unroll
          for (int v = 0; v < 16; ++v) {
            const float m2 = ALPHA * (t01[e * 17 + v] + INV_SQRT3 * t01[1088 + e * 17 + v]);
            atomicAdd(&agg[(size_t)dst * 64 + v], m2);
          }
        } else {
          #pragma unroll
          for (int oo = 0; oo < 16; ++oo) {
            const int qq = (p - 1) * 16 + oo;
            const int v = qq / 3, i = qq - v * 3;
            const float sh = shv_l[e * 3 + i];
            const float m2 = ALPHA * (t2s[e * 17 + v] * sh + t3s[i * 1088 + e * 17 + v]);
            atomicAdd(&agg[(size_t)dst * 64 + 16 + qq], m2);
          }
        }
      }
    }
  }
}

// ---------------------------------------------------------------------------
// Aggregation: wave-per-node, contiguous gather of the node's msg slab.
// ---------------------------------------------------------------------------
__global__ __launch_bounds__(256) void tfn_agg_kernel(const float* __restrict__ msg,
                                                      const int* __restrict__ offs,
                                                      float* __restrict__ out, int N) {
  const int n = blockIdx.x * 4 + (threadIdx.x >> 6);
  const int lane = threadIdx.x & 63;
  if (n >= N) return;
  const int s = offs[n], e = offs[n + 1];
  float acc = 0.0f;
  int j = s;
  for (; j + 1 < e; j += 2) {
    acc += msg[(size_t)j * 64 + lane];
    acc += msg[(size_t)(j + 1) * 64 + lane];
  }
  if (j < e) acc += msg[(size_t)j * 64 + lane];
  out[(size_t)n * 64 + lane] = acc;
}

// ---------------------------------------------------------------------------
// Node kernel: linear mix + gated activations + residual, in place on d_out.
// ---------------------------------------------------------------------------
__global__ __launch_bounds__(256) void tfn_node_kernel(
    const float* __restrict__ nf,
    const float* __restrict__ lw0,
    const float* __restrict__ lw1,
    float* __restrict__ out, int N)
{
  __shared__ float w0s[256], w1s[256];
  const int tid = threadIdx.x;
  w0s[tid] = lw0[tid];
  w1s[tid] = lw1[tid];
  __syncthreads();

  const int n = blockIdx.x * 256 + tid;
  if (n >= N) return;

  float* rowp = out + (size_t)n * 64;
  float as[16], av[16][3];
  #pragma unroll
  for (int u = 0; u < 16; ++u) as[u] = rowp[u];
  #pragma unroll
  for (int u = 0; u < 16; ++u) {
    av[u][0] = rowp[16 + u * 3 + 0];
    av[u][1] = rowp[16 + u * 3 + 1];
    av[u][2] = rowp[16 + u * 3 + 2];
  }
  const float* nfr = nf + (size_t)n * 64;
  float res[64];

  #pragma unroll
  for (int v = 0; v < 16; ++v) {
    float acc = 0.0f;
    #pragma unroll
    for (int u = 0; u < 16; ++u) acc = fmaf(as[u], w0s[u * 16 + v], acc);
    const float ts = 0.25f * acc;
    const float ns = fabsf(ts);
    const float g = (ns / (1.0f + __expf(-ns))) / (ns + 1e-8f);
    res[v] = nfr[v] + ts * g;
  }
  #pragma unroll
  for (int v = 0; v < 16; ++v) {
    float a0 = 0.0f, a1 = 0.0f, a2 = 0.0f;
    #pragma unroll
    for (int u = 0; u < 16; ++u) {
      const float w = w1s[u * 16 + v];
      a0 = fmaf(av[u][0], w, a0);
      a1 = fmaf(av[u][1], w, a1);
      a2 = fmaf(av[u][2], w, a2);
    }
    a0 *= 0.25f; a1 *= 0.25f; a2 *= 0.25f;
    const float nv = sqrtf(a0 * a0 + a1 * a1 + a2 * a2);
    const float g = (nv / (1.0f + __expf(-nv))) / (nv + 1e-8f);
    res[16 + v * 3 + 0] = nfr[16 + v * 3 + 0] + a0 * g;
    res[16 + v * 3 + 1] = nfr[16 + v * 3 + 1] + a1 * g;
    res[16 + v * 3 + 2] = nfr[16 + v * 3 + 2] + a2 * g;
  }
  #pragma unroll
  for (int o = 0; o < 64; o += 4) {
    *(float4*)&rowp[o] = make_float4(res[o], res[o + 1], res[o + 2], res[o + 3]);
  }
}

extern "C" void kernel_launch(void* const* d_in, const int* in_sizes, int n_in,
                              void* d_out, int out_size, void* d_ws, size_t ws_size,
                              hipStream_t stream) {
  const float* nf  = (const float*)d_in[0];
  const float* esh = (const float*)d_in[1];
  const float* emb = (const float*)d_in[2];
  const float* w1  = (const float*)d_in[3];
  const float* b1  = (const float*)d_in[4];
  const float* w2  = (const float*)d_in[5];
  const float* b2  = (const float*)d_in[6];
  const float* lw0 = (const float*)d_in[7];
  const float* lw1 = (const float*)d_in[8];
  const int*   eix = (const int*)d_in[9];

  const int N = in_sizes[0] / 64;
  const int E = in_sizes[9] / 2;
  float* out = (float*)d_out;

  // workspace layout
  char* ws = (char*)d_ws;
  const size_t o_w2t  = 0;
  const size_t o_deg  = 131072;
  const size_t o_offs = o_deg  + (((size_t)N * 4 + 15) & ~(size_t)15);
  const size_t o_rank = o_offs + (((size_t)(N + 1) * 4 + 15) & ~(size_t)15);
  const size_t o_msg  = (o_rank + (size_t)E * 4 + 255) & ~(size_t)255;
  const size_t need   = o_msg + (size_t)E * 256;
  const int posmode = (ws_size >= need) ? 1 : 0;

  unsigned short* w2t = (unsigned short*)(ws + o_w2t);
  int*   deg  = (int*)(ws + o_deg);
  int*   offs = (int*)(ws + o_offs);
  int*   rankp = (int*)(ws + o_rank);
  float* msg  = (float*)(ws + o_msg);

  w2t_kernel<<<dim3(16), dim3(256), 0, stream>>>(w2, w2t);

  const int eblocks = (E + EPB - 1) / EPB;

  if (posmode) {
    hipMemsetAsync(deg, 0, (size_t)N * 4, stream);
    count_kernel<<<dim3((E + 255) / 256), dim3(256), 0, stream>>>(eix, deg, rankp, E);
    scan_kernel<<<dim3(1), dim3(256), 0, stream>>>(deg, offs, N);
    tfn_edge_kernel<<<dim3(eblocks), dim3(256), 0, stream>>>(
        nf, esh, emb, w1, b1, w2t, b2, eix, rankp, offs, msg, out, E, 1);
    tfn_agg_kernel<<<dim3((N + 3) / 4), dim3(256), 0, stream>>>(msg, offs, out, N);
  } else {
    hipMemsetAsync(out, 0, (size_t)out_size * sizeof(float), stream);
    tfn_edge_kernel<<<dim3(eblocks), dim3(256), 0, stream>>>(
        nf, esh, emb, w1, b1, w2t, b2, eix, nullptr, nullptr, nullptr, out, E, 0);
  }

  const int nblocks = (N + 255) / 256;
  tfn_node_kernel<<<dim3(nblocks), dim3(256), 0, stream>>>(nf, lw0, lw1, out, N);
}